// Round 6
// baseline (512.224 us; speedup 1.0000x reference)
//
#include <hip/hip_runtime.h>
#include <hip/hip_cooperative_groups.h>

namespace cg = cooperative_groups;

constexpr int B_ = 8, C_ = 128, L_ = 2048;
constexpr int DEG = 12;           // Taylor degree; 13 coefficients m=0..12
constexpr int NM = DEG + 1;
constexpr int TOK = 16;           // tokens per block
constexpr int NCHUNK = L_ / TOK;  // 128 chunks per batch
constexpr int NBLK = B_ * NCHUNK; // 1024 blocks

// ======================= Cooperative single-kernel path ======================
// 1024 blocks x 256 threads. __launch_bounds__(256,4) caps VGPR at 128 so the
// cooperative-launch co-residency validation (4 blocks/CU) passes.
__global__ __launch_bounds__(256, 4) void fused_all(const float* __restrict__ x,
                                                    const float* __restrict__ W,
                                                    const float* __restrict__ bias,
                                                    float* __restrict__ Part,
                                                    float* __restrict__ Ppow,
                                                    float* __restrict__ G,
                                                    float* __restrict__ out) {
    cg::grid_group grid = cg::this_grid();
    int b     = blockIdx.x >> 7;        // 0..7
    int chunk = blockIdx.x & 127;       // 0..127
    int l0    = chunk << 4;             // 0..2032 step 16
    int tid   = threadIdx.x;

    __shared__ __align__(16) float fT[TOK][132];   // [tok][k]
    __shared__ float Nmom[TOK][14];
    __shared__ float Gs[B_][NM];
    __shared__ float pool_s[C_];
    __shared__ union {
        float Pl[NM][C_];               // phase 2 only
        float augT[C_ * 20];            // phase 3 only ([j][tok] stride 20)
    } u;

    // ---- Phase 1: stage x slice (full 64B lines) + channel partial sums ----
    const float* xb = x + (size_t)b * (C_ * L_);
    #pragma unroll
    for (int r = 0; r < 2; ++r) {
        int flat = tid + 256 * r;       // 0..511 float4s
        int c4 = flat & 3, k = flat >> 2;
        float4 v = *(const float4*)(xb + k * L_ + l0 + 4 * c4);
        fT[4 * c4 + 0][k] = v.x;
        fT[4 * c4 + 1][k] = v.y;
        fT[4 * c4 + 2][k] = v.z;
        fT[4 * c4 + 3][k] = v.w;
    }
    __syncthreads();
    if (tid < C_) {
        float s = 0.f;
        #pragma unroll
        for (int t = 0; t < TOK; ++t) s += fT[t][tid];
        Part[(size_t)blockIdx.x * C_ + tid] = s;
    }
    __threadfence();
    grid.sync();
    __threadfence();                    // reader-side acquire (L2 invalidate)

    // ---- Phase 2: 8 blocks build pooled -> enc -> Ppow, G ----
    if (chunk == 0) {
        if (tid < C_) {
            const volatile float* Pv = (const volatile float*)Part;
            float s = 0.f;
            #pragma unroll 8
            for (int i = 0; i < NCHUNK; ++i)
                s += Pv[(size_t)(b * NCHUNK + i) * C_ + tid];
            pool_s[tid] = s * (1.0f / (float)L_);
        }
        __syncthreads();
        if (tid < C_) {
            float acc = bias[tid];
            const float4* wr = (const float4*)(W + tid * C_);
            #pragma unroll
            for (int j4 = 0; j4 < C_ / 4; ++j4) {
                float4 w4 = wr[j4];
                acc = fmaf(pool_s[4 * j4 + 0], w4.x, acc);
                acc = fmaf(pool_s[4 * j4 + 1], w4.y, acc);
                acc = fmaf(pool_s[4 * j4 + 2], w4.z, acc);
                acc = fmaf(pool_s[4 * j4 + 3], w4.w, acc);
            }
            float t = 1.0f;
            u.Pl[0][tid] = 1.0f;
            Ppow[(b * NM + 0) * C_ + tid] = 1.0f;
            #pragma unroll
            for (int m = 1; m < NM; ++m) {
                t *= acc * (1.0f / (float)m);
                u.Pl[m][tid] = t;
                Ppow[(b * NM + m) * C_ + tid] = t;
            }
        }
        __syncthreads();
        for (int s = 64; s >= 1; s >>= 1) {
            if (tid < s) {
                #pragma unroll
                for (int m = 0; m < NM; ++m) u.Pl[m][tid] += u.Pl[m][tid + s];
            }
            __syncthreads();
        }
        if (tid < NM) G[b * NM + tid] = u.Pl[tid][0];
    }
    __threadfence();
    grid.sync();
    __threadfence();                    // reader-side acquire (L2 invalidate)

    // ---- Phase 3a: stage G; moments via 16-lane token groups ----
    if (tid < B_ * NM) ((float*)Gs)[tid] = ((const volatile float*)G)[tid];
    {
        int tok = tid >> 4;             // 0..15
        int g   = tid & 15;             // 0..15
        int eidx = tok & 7;             // (b*L + l0 + tok) % 8 == tok % 8
        const float4* pr = (const float4*)(Ppow + (size_t)eidx * NM * C_);
        float4 fa = *(const float4*)&fT[tok][8 * g];
        float4 fb = *(const float4*)&fT[tok][8 * g + 4];
        float part[NM];
        #pragma unroll
        for (int m = 0; m < NM; ++m) {
            float4 pa = pr[m * 32 + 2 * g];
            float4 pb = pr[m * 32 + 2 * g + 1];
            part[m] = ((pa.x * fa.x + pa.y * fa.y) + (pa.z * fa.z + pa.w * fa.w))
                    + ((pb.x * fb.x + pb.y * fb.y) + (pb.z * fb.z + pb.w * fb.w));
        }
        #pragma unroll
        for (int mask = 1; mask <= 8; mask <<= 1) {
            #pragma unroll
            for (int m = 0; m < NM; ++m) part[m] += __shfl_xor(part[m], mask, 64);
        }
        if (g == 0) {
            #pragma unroll
            for (int m = 0; m < NM; ++m) Nmom[tok][m] = part[m];
        }
    }
    __syncthreads();

    // ---- Phase 3b: Horner + rcp, staged to LDS ----
    {
        int q     = tid & 7;            // token low bits (== eidx)
        int jbase = (tid >> 3) & 31;
        float Gt[NM], N0[NM], N1[NM];
        #pragma unroll
        for (int m = 0; m < NM; ++m) {
            Gt[m] = Gs[q][m];
            N0[m] = Nmom[q][m];
            N1[m] = Nmom[q + 8][m];
        }
        #pragma unroll
        for (int ji = 0; ji < 4; ++ji) {
            int j = jbase + 32 * ji;
            float s0 = fT[q][j];
            float s1 = fT[q + 8][j];
            float h0 = N0[DEG], g0 = Gt[DEG];
            float h1 = N1[DEG], g1 = Gt[DEG];
            #pragma unroll
            for (int m = DEG - 1; m >= 0; --m) {
                h0 = fmaf(h0, s0, N0[m]);
                g0 = fmaf(g0, s0, Gt[m]);
                h1 = fmaf(h1, s1, N1[m]);
                g1 = fmaf(g1, s1, Gt[m]);
            }
            u.augT[j * 20 + q]     = h0 * __builtin_amdgcn_rcpf(g0);
            u.augT[j * 20 + q + 8] = h1 * __builtin_amdgcn_rcpf(g1);
        }
    }
    __syncthreads();

    // ---- Phase 3c: coalesced float4 stores (full 64B lines) ----
    float* ob = out + (size_t)b * (C_ * L_) + l0;
    #pragma unroll
    for (int r = 0; r < 2; ++r) {
        int flat = tid + 256 * r;       // 0..511 float4s
        int c4 = flat & 3, j = flat >> 2;
        float4 v = *(const float4*)&u.augT[j * 20 + 4 * c4];
        *(float4*)(ob + j * L_ + 4 * c4) = v;
    }
}

// ======================= Fallback 3-kernel path (R4, known-good) =============
__global__ __launch_bounds__(256) void pool_kernel(const float* __restrict__ x,
                                                   float* __restrict__ pooled) {
    int row = blockIdx.x;  // b*C + c, 1024 rows
    const float4* xr = (const float4*)(x + (size_t)row * L_);
    float4 a = xr[threadIdx.x];
    float4 c = xr[threadIdx.x + 256];
    float s = (a.x + a.y) + (a.z + a.w) + (c.x + c.y) + (c.z + c.w);
    #pragma unroll
    for (int off = 32; off; off >>= 1) s += __shfl_down(s, off, 64);
    __shared__ float wsum[4];
    int lane = threadIdx.x & 63, wv = threadIdx.x >> 6;
    if (lane == 0) wsum[wv] = s;
    __syncthreads();
    if (threadIdx.x == 0) {
        float t = (wsum[0] + wsum[1]) + (wsum[2] + wsum[3]);
        pooled[row] = t * (1.0f / (float)L_);
    }
}

__global__ __launch_bounds__(128) void encode_kernel(const float* __restrict__ pooled,
                                                     const float* __restrict__ W,
                                                     const float* __restrict__ bias,
                                                     float* __restrict__ Ppow,
                                                     float* __restrict__ G) {
    int b = blockIdx.x;      // 0..7
    int c = threadIdx.x;     // 0..127
    __shared__ float p[C_];
    p[c] = pooled[b * C_ + c];
    __syncthreads();
    float acc = bias[c];
    const float4* wr = (const float4*)(W + c * C_);
    #pragma unroll
    for (int j4 = 0; j4 < C_ / 4; ++j4) {
        float4 w4 = wr[j4];
        acc = fmaf(p[4 * j4 + 0], w4.x, acc);
        acc = fmaf(p[4 * j4 + 1], w4.y, acc);
        acc = fmaf(p[4 * j4 + 2], w4.z, acc);
        acc = fmaf(p[4 * j4 + 3], w4.w, acc);
    }
    __shared__ float Pl[NM][C_];
    float t = 1.0f;
    Pl[0][c] = 1.0f;
    #pragma unroll
    for (int m = 1; m < NM; ++m) {
        t *= acc * (1.0f / (float)m);
        Pl[m][c] = t;
    }
    #pragma unroll
    for (int m = 0; m < NM; ++m) Ppow[(b * NM + m) * C_ + c] = Pl[m][c];
    __syncthreads();
    for (int s = 64; s >= 1; s >>= 1) {
        if (c < s) {
            #pragma unroll
            for (int m = 0; m < NM; ++m) Pl[m][c] += Pl[m][c + s];
        }
        __syncthreads();
    }
    if (c < NM) G[b * NM + c] = Pl[c][0];
}

__global__ __launch_bounds__(256) void fuse_kernel(const float* __restrict__ x,
                                                   const float* __restrict__ Ppow,
                                                   const float* __restrict__ G,
                                                   float* __restrict__ out) {
    int b = blockIdx.x >> 7;            // 0..7
    int l0 = (blockIdx.x & 127) << 4;   // 0..2032 step 16

    __shared__ __align__(16) float fT[TOK][132];   // [tok][k]
    __shared__ float Nmom[TOK][14];
    __shared__ float Gs[B_][NM];

    int tid = threadIdx.x;
    const float* xb = x + (size_t)b * (C_ * L_);

    #pragma unroll
    for (int r = 0; r < 2; ++r) {
        int flat = tid + 256 * r;       // 0..511 float4s
        int c4 = flat & 3, k = flat >> 2;
        float4 v = *(const float4*)(xb + k * L_ + l0 + 4 * c4);
        fT[4 * c4 + 0][k] = v.x;
        fT[4 * c4 + 1][k] = v.y;
        fT[4 * c4 + 2][k] = v.z;
        fT[4 * c4 + 3][k] = v.w;
    }
    if (tid < B_ * NM) ((float*)Gs)[tid] = G[tid];
    __syncthreads();

    {
        int tok = tid >> 4;             // 0..15
        int g   = tid & 15;             // 0..15
        int eidx = tok & 7;
        const float4* pr = (const float4*)(Ppow + (size_t)eidx * NM * C_);
        float4 fa = *(const float4*)&fT[tok][8 * g];
        float4 fb = *(const float4*)&fT[tok][8 * g + 4];
        float part[NM];
        #pragma unroll
        for (int m = 0; m < NM; ++m) {
            float4 pa = pr[m * 32 + 2 * g];
            float4 pb = pr[m * 32 + 2 * g + 1];
            part[m] = ((pa.x * fa.x + pa.y * fa.y) + (pa.z * fa.z + pa.w * fa.w))
                    + ((pb.x * fb.x + pb.y * fb.y) + (pb.z * fb.z + pb.w * fb.w));
        }
        #pragma unroll
        for (int mask = 1; mask <= 8; mask <<= 1) {
            #pragma unroll
            for (int m = 0; m < NM; ++m) part[m] += __shfl_xor(part[m], mask, 64);
        }
        if (g == 0) {
            #pragma unroll
            for (int m = 0; m < NM; ++m) Nmom[tok][m] = part[m];
        }
    }
    __syncthreads();

    {
        int q     = tid & 7;
        int jbase = (tid >> 3) & 31;
        float Gt[NM], N0[NM], N1[NM];
        #pragma unroll
        for (int m = 0; m < NM; ++m) {
            Gt[m] = Gs[q][m];
            N0[m] = Nmom[q][m];
            N1[m] = Nmom[q + 8][m];
        }
        float* ob = out + (size_t)b * (C_ * L_) + l0;
        #pragma unroll
        for (int ji = 0; ji < 4; ++ji) {
            int j = jbase + 32 * ji;
            float s0 = fT[q][j];
            float s1 = fT[q + 8][j];
            float h0 = N0[DEG], g0 = Gt[DEG];
            float h1 = N1[DEG], g1 = Gt[DEG];
            #pragma unroll
            for (int m = DEG - 1; m >= 0; --m) {
                h0 = fmaf(h0, s0, N0[m]);
                g0 = fmaf(g0, s0, Gt[m]);
                h1 = fmaf(h1, s1, N1[m]);
                g1 = fmaf(g1, s1, Gt[m]);
            }
            ob[j * L_ + q]     = h0 * __builtin_amdgcn_rcpf(g0);
            ob[j * L_ + q + 8] = h1 * __builtin_amdgcn_rcpf(g1);
        }
    }
}

extern "C" void kernel_launch(void* const* d_in, const int* in_sizes, int n_in,
                              void* d_out, int out_size, void* d_ws, size_t ws_size,
                              hipStream_t stream) {
    const float* x    = (const float*)d_in[0];
    const float* W    = (const float*)d_in[1];
    const float* bias = (const float*)d_in[2];
    float* out = (float*)d_out;

    float* Part = (float*)d_ws;               // 1024*128 f32 = 512 KB
    float* Ppow = Part + (size_t)NBLK * C_;   // 8*13*128 f32
    float* G    = Ppow + B_ * NM * C_;        // 104 f32

    void* args[] = {(void*)&x, (void*)&W, (void*)&bias,
                    (void*)&Part, (void*)&Ppow, (void*)&G, (void*)&out};
    hipError_t err = hipLaunchCooperativeKernel((void*)fused_all, dim3(NBLK),
                                                dim3(256), args, 0, stream);
    if (err != hipSuccess) {
        (void)hipGetLastError();   // clear sticky error state
        // Fallback: known-good 3-kernel path. Reuse Part region as pooled.
        float* pooled = Part;
        pool_kernel<<<B_ * C_, 256, 0, stream>>>(x, pooled);
        encode_kernel<<<B_, 128, 0, stream>>>(pooled, W, bias, Ppow, G);
        fuse_kernel<<<B_ * (L_ / TOK), 256, 0, stream>>>(x, Ppow, G, out);
    }
}

// Round 7
// 24.135 us; speedup vs baseline: 21.2230x; 21.2230x over previous
//
#include <hip/hip_runtime.h>

typedef float f32x4 __attribute__((ext_vector_type(4)));

constexpr int B_ = 8, C_ = 128, L_ = 2048;
constexpr int DEG = 12;           // Taylor degree; 13 coefficients m=0..12
constexpr int NM = DEG + 1;
constexpr int TOK = 16;           // tokens per fuse block

__constant__ float c_invfact[NM] = {
    1.0f, 1.0f, 0.5f, 1.0f/6.0f, 1.0f/24.0f, 1.0f/120.0f, 1.0f/720.0f,
    1.0f/5040.0f, 1.0f/40320.0f, 1.0f/362880.0f, 1.0f/3628800.0f,
    1.0f/39916800.0f, 1.0f/479001600.0f};

// ---------------- Kernel 1: pooled[b][c] = mean_l x[b][c][l] ----------------
__global__ __launch_bounds__(256) void pool_kernel(const float* __restrict__ x,
                                                   float* __restrict__ pooled) {
    int row = blockIdx.x;  // b*C + c, 1024 rows
    const float4* xr = (const float4*)(x + (size_t)row * L_);
    float4 a = xr[threadIdx.x];
    float4 c = xr[threadIdx.x + 256];
    float s = (a.x + a.y) + (a.z + a.w) + (c.x + c.y) + (c.z + c.w);
    #pragma unroll
    for (int off = 32; off; off >>= 1) s += __shfl_down(s, off, 64);
    __shared__ float wsum[4];
    int lane = threadIdx.x & 63, wv = threadIdx.x >> 6;
    if (lane == 0) wsum[wv] = s;
    __syncthreads();
    if (threadIdx.x == 0) {
        float t = (wsum[0] + wsum[1]) + (wsum[2] + wsum[3]);
        pooled[row] = t * (1.0f / (float)L_);
    }
}

// -------- Kernel 2: enc = pooled@W.T + b (raw), G[b][m] = sum_k enc^m/m! ----
__global__ __launch_bounds__(128) void encode_kernel(const float* __restrict__ pooled,
                                                     const float* __restrict__ W,
                                                     const float* __restrict__ bias,
                                                     float* __restrict__ enc,
                                                     float* __restrict__ G) {
    int b = blockIdx.x;      // 0..7
    int c = threadIdx.x;     // 0..127
    __shared__ float p[C_];
    p[c] = pooled[b * C_ + c];
    __syncthreads();
    float acc = bias[c];
    const float4* wr = (const float4*)(W + c * C_);
    #pragma unroll
    for (int j4 = 0; j4 < C_ / 4; ++j4) {
        float4 w4 = wr[j4];
        acc = fmaf(p[4 * j4 + 0], w4.x, acc);
        acc = fmaf(p[4 * j4 + 1], w4.y, acc);
        acc = fmaf(p[4 * j4 + 2], w4.z, acc);
        acc = fmaf(p[4 * j4 + 3], w4.w, acc);
    }
    enc[b * C_ + c] = acc;
    __shared__ float Pl[NM][C_];
    float t = 1.0f;
    Pl[0][c] = 1.0f;
    #pragma unroll
    for (int m = 1; m < NM; ++m) {
        t *= acc * (1.0f / (float)m);
        Pl[m][c] = t;
    }
    __syncthreads();
    for (int s = 64; s >= 1; s >>= 1) {
        if (c < s) {
            #pragma unroll
            for (int m = 0; m < NM; ++m) Pl[m][c] += Pl[m][c + s];
        }
        __syncthreads();
    }
    if (c < NM) G[b * NM + c] = Pl[c][0];
}

// ---------------- Kernel 3: polynomial softmax-attention ----------------
// Block: 16 consecutive tokens (same b), 256 threads, 1024 blocks.
// Phase A: stage x slice + enc table (4KB) + G into LDS.
// Phase B: moments via IN-REGISTER power recurrence (p *= e), 16-lane groups,
//          4-level shfl reduce, scale by 1/m! once at writeback.
// Phase C: Horner h/g + rcp -> augT (stride 20) -> coalesced float4 stores.
__global__ __launch_bounds__(256) void fuse_kernel(const float* __restrict__ x,
                                                   const float* __restrict__ enc,
                                                   const float* __restrict__ G,
                                                   float* __restrict__ out) {
    int b = blockIdx.x >> 7;            // 0..7
    int l0 = (blockIdx.x & 127) << 4;   // 0..2032 step 16

    __shared__ __align__(16) float fT[TOK][132];    // [tok][k]
    __shared__ __align__(16) float encs[B_][132];   // [eidx][k], padded
    __shared__ __align__(16) float augT[C_ * 20];   // [j][tok]
    __shared__ float Nmom[TOK][14];
    __shared__ float Gs[B_][NM];

    int tid = threadIdx.x;
    const float* xb = x + (size_t)b * (C_ * L_);

    // ---- Phase A ----
    #pragma unroll
    for (int r = 0; r < 2; ++r) {
        int flat = tid + 256 * r;       // 0..511 float4s
        int c4 = flat & 3, k = flat >> 2;
        float4 v = *(const float4*)(xb + k * L_ + l0 + 4 * c4);
        fT[4 * c4 + 0][k] = v.x;
        fT[4 * c4 + 1][k] = v.y;
        fT[4 * c4 + 2][k] = v.z;
        fT[4 * c4 + 3][k] = v.w;
    }
    {   // enc: 8 rows x 128, one float4 per thread into padded rows
        int e = tid >> 5, c4 = tid & 31;
        *(f32x4*)&encs[e][4 * c4] = *(const f32x4*)(enc + e * C_ + 4 * c4);
    }
    if (tid < B_ * NM) ((float*)Gs)[tid] = G[tid];
    __syncthreads();

    // ---- Phase B: moments ----
    {
        int tok = tid >> 4;             // 0..15
        int g   = tid & 15;             // 0..15
        int eidx = tok & 7;             // (b*L + l0 + tok) % 8 == tok % 8
        f32x4 fa = *(const f32x4*)&fT[tok][8 * g];
        f32x4 fb = *(const f32x4*)&fT[tok][8 * g + 4];
        f32x4 ea = *(const f32x4*)&encs[eidx][8 * g];
        f32x4 eb = *(const f32x4*)&encs[eidx][8 * g + 4];
        float part[NM];
        part[0] = ((fa.x + fa.y) + (fa.z + fa.w)) + ((fb.x + fb.y) + (fb.z + fb.w));
        f32x4 pa = ea, pb = eb;         // e^1
        #pragma unroll
        for (int m = 1; m < NM; ++m) {
            if (m > 1) { pa *= ea; pb *= eb; }   // e^m (raw; scaled at writeback)
            float d = pa.x * fa.x;
            d = fmaf(pa.y, fa.y, d); d = fmaf(pa.z, fa.z, d); d = fmaf(pa.w, fa.w, d);
            d = fmaf(pb.x, fb.x, d); d = fmaf(pb.y, fb.y, d);
            d = fmaf(pb.z, fb.z, d); d = fmaf(pb.w, fb.w, d);
            part[m] = d;
        }
        #pragma unroll
        for (int mask = 1; mask <= 8; mask <<= 1) {
            #pragma unroll
            for (int m = 0; m < NM; ++m) part[m] += __shfl_xor(part[m], mask, 64);
        }
        if (g == 0) {
            #pragma unroll
            for (int m = 0; m < NM; ++m) Nmom[tok][m] = part[m] * c_invfact[m];
        }
    }
    __syncthreads();

    // ---- Phase C: Horner + rcp -> augT ----
    {
        int q     = tid & 7;            // token low bits (== eidx)
        int jbase = (tid >> 3) & 31;
        float Gt[NM], N0[NM], N1[NM];
        #pragma unroll
        for (int m = 0; m < NM; ++m) {
            Gt[m] = Gs[q][m];
            N0[m] = Nmom[q][m];
            N1[m] = Nmom[q + 8][m];
        }
        #pragma unroll
        for (int ji = 0; ji < 4; ++ji) {
            int j = jbase + 32 * ji;
            float s0 = fT[q][j];
            float s1 = fT[q + 8][j];
            float h0 = N0[DEG], g0 = Gt[DEG];
            float h1 = N1[DEG], g1 = Gt[DEG];
            #pragma unroll
            for (int m = DEG - 1; m >= 0; --m) {
                h0 = fmaf(h0, s0, N0[m]);
                g0 = fmaf(g0, s0, Gt[m]);
                h1 = fmaf(h1, s1, N1[m]);
                g1 = fmaf(g1, s1, Gt[m]);
            }
            augT[j * 20 + q]     = h0 * __builtin_amdgcn_rcpf(g0);
            augT[j * 20 + q + 8] = h1 * __builtin_amdgcn_rcpf(g1);
        }
    }
    __syncthreads();

    // ---- Coalesced float4 stores (full 64B lines) ----
    float* ob = out + (size_t)b * (C_ * L_) + l0;
    #pragma unroll
    for (int r = 0; r < 2; ++r) {
        int flat = tid + 256 * r;       // 0..511 float4s
        int c4 = flat & 3, j = flat >> 2;
        float4 v = *(const float4*)&augT[j * 20 + 4 * c4];
        *(float4*)(ob + j * L_ + 4 * c4) = v;
    }
}

extern "C" void kernel_launch(void* const* d_in, const int* in_sizes, int n_in,
                              void* d_out, int out_size, void* d_ws, size_t ws_size,
                              hipStream_t stream) {
    const float* x    = (const float*)d_in[0];
    const float* W    = (const float*)d_in[1];
    const float* bias = (const float*)d_in[2];
    float* out = (float*)d_out;

    float* pooled = (float*)d_ws;            // 1024 f32
    float* enc    = pooled + 1024;           // 1024 f32
    float* G      = enc + B_ * C_;           // 104 f32

    pool_kernel<<<B_ * C_, 256, 0, stream>>>(x, pooled);
    encode_kernel<<<B_, 128, 0, stream>>>(pooled, W, bias, enc, G);
    fuse_kernel<<<B_ * (L_ / TOK), 256, 0, stream>>>(x, enc, G, out);
}